// Round 4
// baseline (158.623 us; speedup 1.0000x reference)
//
#include <hip/hip_runtime.h>
#include <hip/hip_fp16.h>
#include <math.h>

// N=1024, C=128, H=4, HD=32, HID=64
//   u[n,m]   = pos[n,:] @ W1[:,m]       (hid[i,j,m] = (u[i,m]+b1[m]) - u[j,m])
//   A[n,h,m] = sum_d q[n,h*32+d] * W2[m, h*32+d]
//   c[n,h]   = sum_d q[n,h*32+d] * b2[h*32+d]
//   score[h,i,j] = (q_i.k_j)/sqrt(32) + sum_m relu(hid)*A[i,h,m] + c[i,h] - dist(i,j)
//   softmax via exp2 (q pre-scaled RS*log2e; A/c/pos pre-scaled log2e)
//
// R14 (on top of R13's f16 q/k + fdot2):
//   - v stored as f16x2 packed along j-PAIRS (vJ[jp][c]); PV uses
//     v_dot2_f32_f16 with e also packed f16x2 along j-pairs. Halves the
//     biggest L2 stream (v: 512->256 KB/block; total 896->640 KB/block).
//   - e rounded to f16 in-lane; the SAME rounded value feeds lsum (den)
//     and the packed numerator -> rounding bias cancels in num/den.
//   - kT regrouped: per (cb,j) the 4 head-quads live in 8 contiguous u32
//     -> 2x dwordx4 loads per cb (was 4x dwordx2). u stream: uint4 groups
//     of 2 mb -> 8x dwordx4 (was 16x dwordx2).
//
// ws layout (floats):
//   qT   u32[1024][64] f16x2 pairs                    @ 0
//   vJ   u32[512][128]: f16x2 (v[2jp][c], v[2jp+1][c]) @ 131072
//   kT8  u32[8][1024][8]: f16x2 k quads grouped       @ 262144
//   uT4  u32[8][1024][4]: bf16x2 u quads grouped      @ 327680
//   sA   [1024][328]                                  @ 360448
//   pos4 [1024][4] (x L2E)                            @ 696320

typedef float v2f __attribute__((ext_vector_type(2)));
typedef float v4f __attribute__((ext_vector_type(4)));
typedef __fp16 h2f __attribute__((ext_vector_type(2)));

#define L2E 1.4426950408889634f
#define RSL (0.17677669529663687f * L2E)

static __device__ __forceinline__ float dot4(float4 a, float4 b) {
  return a.x*b.x + a.y*b.y + a.z*b.z + a.w*b.w;
}
static __device__ __forceinline__ v2f fma2(v2f a, v2f b, v2f c) {
  return __builtin_elementwise_fma(a, b, c);
}
static __device__ __forceinline__ unsigned int bfr(float f) {   // fp32 -> bf16 (RNE)
  unsigned int b = __float_as_uint(f);
  return (b + 0x7fffu + ((b >> 16) & 1u)) >> 16;
}
static __device__ __forceinline__ unsigned int pack2(float lo, float hi) {
  return bfr(lo) | (bfr(hi) << 16);
}
static __device__ __forceinline__ v2f unpk(unsigned int a) {    // bf16x2 -> 2x fp32
  v2f r;
  r.x = __uint_as_float(a << 16);
  r.y = __uint_as_float(a & 0xffff0000u);
  return r;
}
static __device__ __forceinline__ unsigned int pkh(float lo, float hi) { // f16x2 (RTZ)
  h2f r = __builtin_amdgcn_cvt_pkrtz(lo, hi);
  return __builtin_bit_cast(unsigned int, r);
}
static __device__ __forceinline__ unsigned int pkrn(float lo, float hi) { // f16x2 (RNE)
  unsigned int a = (unsigned int)__half_as_ushort(__float2half(lo));
  unsigned int b = (unsigned int)__half_as_ushort(__float2half(hi));
  return a | (b << 16);
}
static __device__ __forceinline__ float fdot2h(unsigned int a_, unsigned int b_, float acc) {
  return __builtin_amdgcn_fdot2(__builtin_bit_cast(h2f, a_),
                                __builtin_bit_cast(h2f, b_), acc, false);
}
// round f32 -> f16 (RTZ), return rounded value as f32 and the f16 bits
static __device__ __forceinline__ float r2h(float x, unsigned int* bits) {
  h2f t = __builtin_amdgcn_cvt_pkrtz(x, x);
  *bits = __builtin_bit_cast(unsigned int, t) & 0xffffu;
  return (float)t.x;
}

// ---------------- K1: precompute ------------------------------------------
// 512 blocks x 384 thr; block = 2 rows.
__global__ __launch_bounds__(384) void k_pre(
    const float* __restrict__ x, const float* __restrict__ y, const float* __restrict__ pos,
    const float* __restrict__ Wq, const float* __restrict__ bq,
    const float* __restrict__ Wk, const float* __restrict__ bk,
    const float* __restrict__ Wv, const float* __restrict__ bv,
    const float* __restrict__ W1, const float* __restrict__ b1,
    const float* __restrict__ W2, const float* __restrict__ b2,
    unsigned int* __restrict__ qT, unsigned int* __restrict__ vJ,
    unsigned int* __restrict__ kT8, unsigned int* __restrict__ uT4,
    float* __restrict__ sA, float* __restrict__ pos4w)
{
  __shared__ float xs[256], ys[256], qs[256];
  __shared__ __align__(16) float4 W2S[64*33];

  const int t  = threadIdx.x;
  const int n0 = blockIdx.x * 2;

  if (t < 256) { xs[t] = x[n0*128 + t]; ys[t] = y[n0*128 + t]; }
  {
    const float4* w2g = (const float4*)W2;
    #pragma unroll
    for (int r = 0; r < 6; ++r) {
      const int e = t + 384*r;
      if (e < 2048) W2S[(e>>5)*33 + (e&31)] = w2g[e];
    }
  }
  __syncthreads();

  {
    const int c   = t & 127;
    const int mat = t >> 7;                 // wave-uniform
    const float* W    = (mat == 0) ? Wq : (mat == 1 ? Wk : Wv);
    const float* S    = (mat == 0) ? xs : ys;
    const float* bias = (mat == 0) ? bq : (mat == 1 ? bk : bv);
    float a0 = 0.f, a1 = 0.f;
    #pragma unroll 8
    for (int d = 0; d < 128; ++d) {
      const float w_ = W[d*128 + c];
      a0 = fmaf(S[d],       w_, a0);
      a1 = fmaf(S[128 + d], w_, a1);
    }
    const float bb = bias[c];
    a0 += bb; a1 += bb;
    if (mat == 0) {
      qs[c] = a0; qs[128 + c] = a1;
      // q: pack adjacent columns into f16x2 pairs (pre-scaled by RSL)
      const float sa0 = a0 * RSL, sa1 = a1 * RSL;
      const float tb0 = __shfl_xor(sa0, 1);
      const float tb1 = __shfl_xor(sa1, 1);
      if ((c & 1) == 0) {
        qT[(n0  )*64 + (c>>1)] = pkh(sa0, tb0);
        qT[(n0+1)*64 + (c>>1)] = pkh(sa1, tb1);
      }
    } else if (mat == 2) {
      // v: pack adjacent ROWS (n0, n0+1) per column -> f16x2 (RNE)
      vJ[(n0>>1)*128 + c] = pkrn(a0, a1);
    } else {
      // k: pack adjacent columns via in-wave exchange; grouped layout:
      // kT8[(cb*1024 + n)*8 + slot*2 + wrd], qi=c>>2, cb=qi&7, slot=qi>>3
      const float b0 = __shfl_xor(a0, 1);
      const float b1 = __shfl_xor(a1, 1);
      if ((c & 1) == 0) {
        const int qi = c >> 2, cbv = qi & 7, slot = qi >> 3, wrd = (c >> 1) & 1;
        const int base = (cbv*1024 + n0)*8 + slot*2 + wrd;
        kT8[base]     = pkh(a0, b0);
        kT8[base + 8] = pkh(a1, b1);
      }
    }
  }
  __syncthreads();

  if (t < 256) {
    const int m = t & 63, h = t >> 6;
    const float4* qs4 = (const float4*)qs;
    #pragma unroll
    for (int ii = 0; ii < 2; ++ii) {
      float acc = 0.f;
      #pragma unroll
      for (int ch = 0; ch < 8; ++ch)
        acc += dot4(qs4[ii*32 + h*8 + ch], W2S[m*33 + h*8 + ch]);
      sA[(n0+ii)*328 + 8 + (m>>2)*20 + h*4 + (m&3)] = acc * L2E;
    }
    if (t < 8) {
      const int ii = t >> 2, h2 = t & 3;
      float ca = 0.f;
      #pragma unroll
      for (int d = 0; d < 32; ++d) ca = fmaf(qs[ii*128 + h2*32 + d], b2[h2*32 + d], ca);
      sA[(n0+ii)*328 + h2] = ca * L2E;
    } else if (t < 16) {
      const int tt = t-8, ii = tt>>2, cc = tt&3;
      sA[(n0+ii)*328 + 4 + cc] = (cc < 3) ? pos[(n0+ii)*3 + cc] * L2E : 0.f;
    } else if (t < 24) {
      const int tt = t-16, ii = tt>>2, cc = tt&3;
      pos4w[(n0+ii)*4 + cc] = (cc < 3) ? pos[(n0+ii)*3 + cc] * L2E : 0.f;
    }
  } else if (t < 320) {
    // u: thread = (ii, m-pair); grouped layout:
    // uT4[((mp>>2)*1024 + n)*4 + (mp&3)]
    const int tt = t - 256, ii = tt >> 5, mp = tt & 31;
    const int m0 = mp * 2;
    float ua0 = 0.f, ua1 = 0.f;
    #pragma unroll
    for (int cc = 0; cc < 3; ++cc) {
      const float p = pos[(n0+ii)*3 + cc];
      ua0 = fmaf(p, W1[cc*64 + m0    ], ua0);
      ua1 = fmaf(p, W1[cc*64 + m0 + 1], ua1);
    }
    sA[(n0+ii)*328 + 8 + (m0>>2)*20 + 16 + (m0&3)    ] = ua0 + b1[m0];
    sA[(n0+ii)*328 + 8 + (m0>>2)*20 + 16 + (m0&3) + 1] = ua1 + b1[m0+1];
    uT4[((mp>>2)*1024 + (n0+ii))*4 + (mp&3)] = pack2(ua0, ua1);
  }
}

// ---------------- K2: fused scores + softmax + PV + direct out -------------
// 512 blocks x 1024 thr (16 waves). Block = 2 i-rows x ALL j; wave w = j-tile w.
__global__ __launch_bounds__(1024, 8) void k_attn(
    const unsigned int* __restrict__ qT, const unsigned int* __restrict__ vJ,
    const unsigned int* __restrict__ kT8, const unsigned int* __restrict__ uT4,
    const float* __restrict__ sA, const v4f* __restrict__ pos4,
    float* __restrict__ out)
{
  __shared__ __align__(16) unsigned int eL16[16*272]; // per-wave: [r=ii*4+h][34 jp] f16x2
  __shared__ __align__(16) float rnum[8192];          // v4f [w][ii][rep][c4]
  __shared__ float rden[128];                         // [w][ii*4+h]

  const int t     = threadIdx.x;
  const int i0    = blockIdx.x * 2;
  const int w     = t >> 6;                    // 0..15 = j-tile
  const int lane  = t & 63;
  const int c4    = lane & 31;
  const int rep   = lane >> 5;
  const int hh    = c4 >> 3;

  const int jb = w*64;
  const int j  = jb + lane;

  const float* sA0 = sA + i0*328;              // uniform -> scalar loads
  const float* sA1 = sA0 + 328;

  const float c00 = sA0[0], c01 = sA0[1], c02 = sA0[2], c03 = sA0[3];
  const float c10 = sA1[0], c11 = sA1[1], c12 = sA1[2], c13 = sA1[3];
  const float p0x = sA0[4], p0y = sA0[5], p0z = sA0[6];
  const float p1x = sA1[4], p1y = sA1[5], p1z = sA1[6];

  const v4f pj = pos4[j];
  const float d0x = p0x-pj.x, d0y = p0y-pj.y, d0z = p0z-pj.z;
  const float d1x = p1x-pj.x, d1y = p1y-pj.y, d1z = p1z-pj.z;
  const float dist0 = sqrtf(d0x*d0x + d0y*d0y + d0z*d0z);
  const float dist1 = sqrtf(d1x*d1x + d1y*d1y + d1z*d1z);

  // ---- geom (packed math, bf16 u stream, uint4-grouped) ----
  v2f g0a={0.f,0.f}, g0b={0.f,0.f}, g0c={0.f,0.f}, g0d={0.f,0.f};
  v2f g1a={0.f,0.f}, g1b={0.f,0.f}, g1c={0.f,0.f}, g1d={0.f,0.f};
  {
    const uint4* ug = (const uint4*)uT4;
#define GEOM_MB(MB, W01, W23) { \
    const v2f uj01 = unpk(W01), uj23 = unpk(W23); \
    const v2f z = {0.f, 0.f}; \
    { \
      const float* ab = sA0 + 8 + (MB)*20; \
      const v2f h01 = __builtin_elementwise_max(*(const v2f*)(ab+16) - uj01, z); \
      const v2f h23 = __builtin_elementwise_max(*(const v2f*)(ab+18) - uj23, z); \
      g0a = fma2(h01, *(const v2f*)(ab+ 0), g0a); g0a = fma2(h23, *(const v2f*)(ab+ 2), g0a); \
      g0b = fma2(h01, *(const v2f*)(ab+ 4), g0b); g0b = fma2(h23, *(const v2f*)(ab+ 6), g0b); \
      g0c = fma2(h01, *(const v2f*)(ab+ 8), g0c); g0c = fma2(h23, *(const v2f*)(ab+10), g0c); \
      g0d = fma2(h01, *(const v2f*)(ab+12), g0d); g0d = fma2(h23, *(const v2f*)(ab+14), g0d); \
    } \
    { \
      const float* ab = sA1 + 8 + (MB)*20; \
      const v2f h01 = __builtin_elementwise_max(*(const v2f*)(ab+16) - uj01, z); \
      const v2f h23 = __builtin_elementwise_max(*(const v2f*)(ab+18) - uj23, z); \
      g1a = fma2(h01, *(const v2f*)(ab+ 0), g1a); g1a = fma2(h23, *(const v2f*)(ab+ 2), g1a); \
      g1b = fma2(h01, *(const v2f*)(ab+ 4), g1b); g1b = fma2(h23, *(const v2f*)(ab+ 6), g1b); \
      g1c = fma2(h01, *(const v2f*)(ab+ 8), g1c); g1c = fma2(h23, *(const v2f*)(ab+10), g1c); \
      g1d = fma2(h01, *(const v2f*)(ab+12), g1d); g1d = fma2(h23, *(const v2f*)(ab+14), g1d); \
    } \
  }
    #pragma unroll 2
    for (int g = 0; g < 8; ++g) {
      const uint4 uw = ug[g*1024 + j];
      GEOM_MB(2*g,     uw.x, uw.y)
      GEOM_MB(2*g + 1, uw.z, uw.w)
    }
#undef GEOM_MB
  }

  // collapse geom v2f accumulators to scalars; qk adds into the scalars
  float t0a = g0a.x + g0a.y, t0b = g0b.x + g0b.y;
  float t0c = g0c.x + g0c.y, t0d = g0d.x + g0d.y;
  float t1a = g1a.x + g1a.y, t1b = g1b.x + g1b.y;
  float t1c = g1c.x + g1c.y, t1d = g1d.x + g1d.y;

  // ---- qk via v_dot2_f32_f16 (grouped kT8: 2 x dwordx4 per cb) ----
  {
    const uint4* kg = (const uint4*)kT8;
    const unsigned int* qT0 = qT + i0*64;
    const unsigned int* qT1 = qT0 + 64;
    #pragma unroll 8
    for (int cb = 0; cb < 8; ++cb) {
      const uint4 ka = kg[(cb*1024 + j)*2];
      const uint4 kb = kg[(cb*1024 + j)*2 + 1];
      t0a = fdot2h(ka.x, qT0[     cb*2], t0a); t0a = fdot2h(ka.y, qT0[     cb*2+1], t0a);
      t0b = fdot2h(ka.z, qT0[16 + cb*2], t0b); t0b = fdot2h(ka.w, qT0[16 + cb*2+1], t0b);
      t0c = fdot2h(kb.x, qT0[32 + cb*2], t0c); t0c = fdot2h(kb.y, qT0[32 + cb*2+1], t0c);
      t0d = fdot2h(kb.z, qT0[48 + cb*2], t0d); t0d = fdot2h(kb.w, qT0[48 + cb*2+1], t0d);
      t1a = fdot2h(ka.x, qT1[     cb*2], t1a); t1a = fdot2h(ka.y, qT1[     cb*2+1], t1a);
      t1b = fdot2h(ka.z, qT1[16 + cb*2], t1b); t1b = fdot2h(ka.w, qT1[16 + cb*2+1], t1b);
      t1c = fdot2h(kb.x, qT1[32 + cb*2], t1c); t1c = fdot2h(kb.y, qT1[32 + cb*2+1], t1c);
      t1d = fdot2h(kb.z, qT1[48 + cb*2], t1d); t1d = fdot2h(kb.w, qT1[48 + cb*2+1], t1d);
    }
  }

  // ---- exp2 numerators; round to f16 in-lane (same value feeds num AND den),
  //      pack j-pairs across adjacent lanes -> eL16 ----
  float lsum[8];
  unsigned int eb[8];
  lsum[0] = r2h(exp2f(t0a + (c00 - dist0)), &eb[0]);
  lsum[1] = r2h(exp2f(t0b + (c01 - dist0)), &eb[1]);
  lsum[2] = r2h(exp2f(t0c + (c02 - dist0)), &eb[2]);
  lsum[3] = r2h(exp2f(t0d + (c03 - dist0)), &eb[3]);
  lsum[4] = r2h(exp2f(t1a + (c10 - dist1)), &eb[4]);
  lsum[5] = r2h(exp2f(t1b + (c11 - dist1)), &eb[5]);
  lsum[6] = r2h(exp2f(t1c + (c12 - dist1)), &eb[6]);
  lsum[7] = r2h(exp2f(t1d + (c13 - dist1)), &eb[7]);
  {
    unsigned int* eW = &eL16[w*272];
    const int jp = lane >> 1;
    #pragma unroll
    for (int r8 = 0; r8 < 8; ++r8) {
      const unsigned int pb = __shfl_xor(eb[r8], 1);
      if ((lane & 1) == 0) eW[r8*34 + jp] = eb[r8] | (pb << 16);
    }
  }
  __builtin_amdgcn_wave_barrier();

  // ---- denominator reduce first (frees lsum before PV raises pressure) ----
  #pragma unroll
  for (int mm = 1; mm < 64; mm <<= 1) {
    #pragma unroll
    for (int r8 = 0; r8 < 8; ++r8) lsum[r8] += __shfl_xor(lsum[r8], mm);
  }
  if (lane == 0) {
    #pragma unroll
    for (int r8 = 0; r8 < 8; ++r8) rden[w*8 + r8] = lsum[r8];
  }

  // ---- PV: lane owns col-quad c4 (head hh), rep = jp-half of tile.
  //      out[c] += sum_jp dot2((e[2jp],e[2jp+1]), (v[2jp][c],v[2jp+1][c])) ----
  v4f acc0 = {0.f,0.f,0.f,0.f};
  v4f acc1 = {0.f,0.f,0.f,0.f};
  {
    const unsigned int* eW0 = &eL16[w*272 +  hh   *34 + rep*16];
    const unsigned int* eW1 = &eL16[w*272 + (4+hh)*34 + rep*16];
    const uint4* vg = (const uint4*)vJ + (w*32 + rep*16)*32 + c4;
    #pragma unroll 4
    for (int m = 0; m < 16; ++m) {
      const uint4 vw = vg[m*32];
      const unsigned int e0 = eW0[m];
      const unsigned int e1 = eW1[m];
      acc0.x = fdot2h(vw.x, e0, acc0.x); acc0.y = fdot2h(vw.y, e0, acc0.y);
      acc0.z = fdot2h(vw.z, e0, acc0.z); acc0.w = fdot2h(vw.w, e0, acc0.w);
      acc1.x = fdot2h(vw.x, e1, acc1.x); acc1.y = fdot2h(vw.y, e1, acc1.y);
      acc1.z = fdot2h(vw.z, e1, acc1.z); acc1.w = fdot2h(vw.w, e1, acc1.w);
    }
  }
  __builtin_amdgcn_wave_barrier();

  // ---- in-block reduce across 16 waves ----
  ((v4f*)rnum)[((w*2+0)*2 + rep)*32 + c4] = acc0;
  ((v4f*)rnum)[((w*2+1)*2 + rep)*32 + c4] = acc1;
  __syncthreads();

  if (t < 256) {
    const int ii = t >> 7, c = t & 127;
    float num = 0.f, den = 0.f;
    #pragma unroll
    for (int ww = 0; ww < 16; ++ww) {
      num += rnum[((ww*2+ii)*2+0)*128 + c];
      num += rnum[((ww*2+ii)*2+1)*128 + c];
      den += rden[ww*8 + ii*4 + (c>>5)];
    }
    out[(i0+ii)*128 + c] = num / den;
  }
}

extern "C" void kernel_launch(void* const* d_in, const int* in_sizes, int n_in,
                              void* d_out, int out_size, void* d_ws, size_t ws_size,
                              hipStream_t stream) {
  const float* x   = (const float*)d_in[0];
  const float* y   = (const float*)d_in[1];
  const float* pos = (const float*)d_in[2];
  const float* Wq  = (const float*)d_in[3];
  const float* bq  = (const float*)d_in[4];
  const float* Wk  = (const float*)d_in[5];
  const float* bk  = (const float*)d_in[6];
  const float* Wv  = (const float*)d_in[7];
  const float* bv  = (const float*)d_in[8];
  const float* W1  = (const float*)d_in[9];
  const float* b1  = (const float*)d_in[10];
  const float* W2  = (const float*)d_in[11];
  const float* b2  = (const float*)d_in[12];

  float* ws = (float*)d_ws;
  unsigned int* qT   = (unsigned int*)ws;               // 65536 u32 (region 131072 f)
  unsigned int* vJ   = (unsigned int*)(ws + 131072);    // 65536 u32 (region 131072 f)
  unsigned int* kT8  = (unsigned int*)(ws + 262144);    // 65536 u32
  unsigned int* uT4  = (unsigned int*)(ws + 327680);    // 32768 u32
  float*        sA   = ws + 360448;                     // 335872
  float*        pos4 = ws + 696320;                     // 4096
  float*        out  = (float*)d_out;

  k_pre<<<dim3(512), dim3(384), 0, stream>>>(x, y, pos, Wq, bq, Wk, bk, Wv, bv,
                                             W1, b1, W2, b2,
                                             qT, vJ, kT8, uT4, sA, pos4);
  k_attn<<<dim3(512), dim3(1024), 0, stream>>>(qT, vJ, kT8, uT4, sA,
                                               (const v4f*)pos4, out);
}

// Round 5
// 114.115 us; speedup vs baseline: 1.3900x; 1.3900x over previous
//
#include <hip/hip_runtime.h>
#include <hip/hip_fp16.h>
#include <math.h>

// N=1024, C=128, H=4, HD=32, HID=64
//   u[n,m]   = pos[n,:] @ W1[:,m]       (hid[i,j,m] = (u[i,m]+b1[m]) - u[j,m])
//   A[n,h,m] = sum_d q[n,h*32+d] * W2[m, h*32+d]
//   c[n,h]   = sum_d q[n,h*32+d] * b2[h*32+d]
//   score[h,i,j] = (q_i.k_j)/sqrt(32) + sum_m relu(hid)*A[i,h,m] + c[i,h] - dist(i,j)
//   softmax via exp2 (q pre-scaled RS*log2e; A/c/pos pre-scaled log2e)
//
// R15 = R13 (115.0 us, known-good register allocation) + ONE change:
//   v stored as f16x2 packed over j-pairs (vJ); PV uses v_dot2_f32_f16.
//   Halves the largest L2 stream (v 512->256 KB/block). e stays in R13's
//   f32 eL layout (stores unchanged) but is rounded to f16-representable
//   in-lane first; den sums the rounded value and PV re-packs pairs with
//   cvt_pkrtz (exact on rounded values) -> num/den consistent.
//   R14's spill cascade (VGPR 32 + 88 MB scratch writes) came from the
//   eb[8]+shfl-pack live range under the 64-VGPR cap; this version adds
//   ~2 temps over R13.
//
// ws layout (floats):
//   qT   u32[1024][64] f16x2 pairs                    @ 0
//   vJ   u32[512][128]: f16x2 (v[2jp][c], v[2jp+1][c]) @ 131072
//   kTb  u32[32][1024][2]: f16x2 k quads              @ 262144
//   uTb  u32[16][1024][2]: bf16x2 u quads             @ 327680
//   sA   [1024][328]                                  @ 360448
//   pos4 [1024][4] (x L2E)                            @ 696320

typedef float v2f __attribute__((ext_vector_type(2)));
typedef float v4f __attribute__((ext_vector_type(4)));
typedef __fp16 h2f __attribute__((ext_vector_type(2)));

#define L2E 1.4426950408889634f
#define RSL (0.17677669529663687f * L2E)

static __device__ __forceinline__ float dot4(float4 a, float4 b) {
  return a.x*b.x + a.y*b.y + a.z*b.z + a.w*b.w;
}
static __device__ __forceinline__ v2f fma2(v2f a, v2f b, v2f c) {
  return __builtin_elementwise_fma(a, b, c);
}
static __device__ __forceinline__ unsigned int bfr(float f) {   // fp32 -> bf16 (RNE)
  unsigned int b = __float_as_uint(f);
  return (b + 0x7fffu + ((b >> 16) & 1u)) >> 16;
}
static __device__ __forceinline__ unsigned int pack2(float lo, float hi) {
  return bfr(lo) | (bfr(hi) << 16);
}
static __device__ __forceinline__ v2f unpk(unsigned int a) {    // bf16x2 -> 2x fp32
  v2f r;
  r.x = __uint_as_float(a << 16);
  r.y = __uint_as_float(a & 0xffff0000u);
  return r;
}
static __device__ __forceinline__ unsigned int pkh(float lo, float hi) { // f16x2 (RTZ)
  h2f r = __builtin_amdgcn_cvt_pkrtz(lo, hi);
  return __builtin_bit_cast(unsigned int, r);
}
static __device__ __forceinline__ unsigned int pkrn(float lo, float hi) { // f16x2 (RNE)
  unsigned int a = (unsigned int)__half_as_ushort(__float2half(lo));
  unsigned int b = (unsigned int)__half_as_ushort(__float2half(hi));
  return a | (b << 16);
}
static __device__ __forceinline__ float fdot2h(unsigned int a_, unsigned int b_, float acc) {
  return __builtin_amdgcn_fdot2(__builtin_bit_cast(h2f, a_),
                                __builtin_bit_cast(h2f, b_), acc, false);
}
static __device__ __forceinline__ float r2hf(float x) { // round f32 to f16-representable
  h2f t = __builtin_amdgcn_cvt_pkrtz(x, x);
  return (float)t.x;
}

// ---------------- K1: precompute ------------------------------------------
// 512 blocks x 384 thr; block = 2 rows.
__global__ __launch_bounds__(384) void k_pre(
    const float* __restrict__ x, const float* __restrict__ y, const float* __restrict__ pos,
    const float* __restrict__ Wq, const float* __restrict__ bq,
    const float* __restrict__ Wk, const float* __restrict__ bk,
    const float* __restrict__ Wv, const float* __restrict__ bv,
    const float* __restrict__ W1, const float* __restrict__ b1,
    const float* __restrict__ W2, const float* __restrict__ b2,
    unsigned int* __restrict__ qT, unsigned int* __restrict__ vJ,
    unsigned int* __restrict__ kTb, unsigned int* __restrict__ uTb,
    float* __restrict__ sA, float* __restrict__ pos4w)
{
  __shared__ float xs[256], ys[256], qs[256];
  __shared__ __align__(16) float4 W2S[64*33];

  const int t  = threadIdx.x;
  const int n0 = blockIdx.x * 2;

  if (t < 256) { xs[t] = x[n0*128 + t]; ys[t] = y[n0*128 + t]; }
  {
    const float4* w2g = (const float4*)W2;
    #pragma unroll
    for (int r = 0; r < 6; ++r) {
      const int e = t + 384*r;
      if (e < 2048) W2S[(e>>5)*33 + (e&31)] = w2g[e];
    }
  }
  __syncthreads();

  {
    const int c   = t & 127;
    const int mat = t >> 7;                 // wave-uniform
    const float* W    = (mat == 0) ? Wq : (mat == 1 ? Wk : Wv);
    const float* S    = (mat == 0) ? xs : ys;
    const float* bias = (mat == 0) ? bq : (mat == 1 ? bk : bv);
    float a0 = 0.f, a1 = 0.f;
    #pragma unroll 8
    for (int d = 0; d < 128; ++d) {
      const float w_ = W[d*128 + c];
      a0 = fmaf(S[d],       w_, a0);
      a1 = fmaf(S[128 + d], w_, a1);
    }
    const float bb = bias[c];
    a0 += bb; a1 += bb;
    if (mat == 0) {
      qs[c] = a0; qs[128 + c] = a1;
      // q: pack adjacent columns into f16x2 pairs (pre-scaled by RSL)
      const float sa0 = a0 * RSL, sa1 = a1 * RSL;
      const float tb0 = __shfl_xor(sa0, 1);
      const float tb1 = __shfl_xor(sa1, 1);
      if ((c & 1) == 0) {
        qT[(n0  )*64 + (c>>1)] = pkh(sa0, tb0);
        qT[(n0+1)*64 + (c>>1)] = pkh(sa1, tb1);
      }
    } else if (mat == 2) {
      // v: pack the two rows (n0, n0+1) per column -> f16x2 (RNE)
      vJ[(n0>>1)*128 + c] = pkrn(a0, a1);
    } else {
      // k: pack adjacent columns into pairs via in-wave exchange
      const float b0 = __shfl_xor(a0, 1);
      const float b1 = __shfl_xor(a1, 1);
      if ((c & 1) == 0) {
        const int idx = ((c>>2)*1024)*2 + ((c>>1)&1);
        kTb[idx + (n0  )*2] = pkh(a0, b0);
        kTb[idx + (n0+1)*2] = pkh(a1, b1);
      }
    }
  }
  __syncthreads();

  if (t < 256) {
    const int m = t & 63, h = t >> 6;
    const float4* qs4 = (const float4*)qs;
    #pragma unroll
    for (int ii = 0; ii < 2; ++ii) {
      float acc = 0.f;
      #pragma unroll
      for (int ch = 0; ch < 8; ++ch)
        acc += dot4(qs4[ii*32 + h*8 + ch], W2S[m*33 + h*8 + ch]);
      sA[(n0+ii)*328 + 8 + (m>>2)*20 + h*4 + (m&3)] = acc * L2E;
    }
    if (t < 8) {
      const int ii = t >> 2, h2 = t & 3;
      float ca = 0.f;
      #pragma unroll
      for (int d = 0; d < 32; ++d) ca = fmaf(qs[ii*128 + h2*32 + d], b2[h2*32 + d], ca);
      sA[(n0+ii)*328 + h2] = ca * L2E;
    } else if (t < 16) {
      const int tt = t-8, ii = tt>>2, cc = tt&3;
      sA[(n0+ii)*328 + 4 + cc] = (cc < 3) ? pos[(n0+ii)*3 + cc] * L2E : 0.f;
    } else if (t < 24) {
      const int tt = t-16, ii = tt>>2, cc = tt&3;
      pos4w[(n0+ii)*4 + cc] = (cc < 3) ? pos[(n0+ii)*3 + cc] * L2E : 0.f;
    }
  } else if (t < 320) {
    // u: thread = (ii, m-pair); computes 2 adjacent m -> one bf16x2 word
    const int tt = t - 256, ii = tt >> 5, mp = tt & 31;
    const int m0 = mp * 2;
    float ua0 = 0.f, ua1 = 0.f;
    #pragma unroll
    for (int cc = 0; cc < 3; ++cc) {
      const float p = pos[(n0+ii)*3 + cc];
      ua0 = fmaf(p, W1[cc*64 + m0    ], ua0);
      ua1 = fmaf(p, W1[cc*64 + m0 + 1], ua1);
    }
    sA[(n0+ii)*328 + 8 + (m0>>2)*20 + 16 + (m0&3)    ] = ua0 + b1[m0];
    sA[(n0+ii)*328 + 8 + (m0>>2)*20 + 16 + (m0&3) + 1] = ua1 + b1[m0+1];
    uTb[((mp>>1)*1024 + (n0+ii))*2 + (mp&1)] = pack2(ua0, ua1);
  }
}

// ---------------- K2: fused scores + softmax + PV + direct out -------------
// 512 blocks x 1024 thr (16 waves). Block = 2 i-rows x ALL j; wave w = j-tile w.
__global__ __launch_bounds__(1024, 8) void k_attn(
    const unsigned int* __restrict__ qT, const unsigned int* __restrict__ vJ,
    const uint2* __restrict__ kTb, const uint2* __restrict__ uTb,
    const float* __restrict__ sA, const v4f* __restrict__ pos4,
    float* __restrict__ out)
{
  __shared__ __align__(16) float eL[16*544];   // per-wave E: [(ii*4+h)*68 + j]
  __shared__ __align__(16) float rnum[8192];   // v4f [w][ii][rep][c4]
  __shared__ float rden[128];                  // [w][ii*4+h]

  const int t     = threadIdx.x;
  const int i0    = blockIdx.x * 2;
  const int w     = t >> 6;                    // 0..15 = j-tile
  const int lane  = t & 63;
  const int c4    = lane & 31;
  const int rep   = lane >> 5;
  const int hh    = c4 >> 3;

  const int jb = w*64;
  const int j  = jb + lane;

  const float* sA0 = sA + i0*328;              // uniform -> scalar loads
  const float* sA1 = sA0 + 328;

  const float c00 = sA0[0], c01 = sA0[1], c02 = sA0[2], c03 = sA0[3];
  const float c10 = sA1[0], c11 = sA1[1], c12 = sA1[2], c13 = sA1[3];
  const float p0x = sA0[4], p0y = sA0[5], p0z = sA0[6];
  const float p1x = sA1[4], p1y = sA1[5], p1z = sA1[6];

  const v4f pj = pos4[j];
  const float d0x = p0x-pj.x, d0y = p0y-pj.y, d0z = p0z-pj.z;
  const float d1x = p1x-pj.x, d1y = p1y-pj.y, d1z = p1z-pj.z;
  const float dist0 = sqrtf(d0x*d0x + d0y*d0y + d0z*d0z);
  const float dist1 = sqrtf(d1x*d1x + d1y*d1y + d1z*d1z);

  // ---- geom (packed math, bf16 u stream) ----
  v2f g0a={0.f,0.f}, g0b={0.f,0.f}, g0c={0.f,0.f}, g0d={0.f,0.f};
  v2f g1a={0.f,0.f}, g1b={0.f,0.f}, g1c={0.f,0.f}, g1d={0.f,0.f};
  #pragma unroll 4
  for (int mb = 0; mb < 16; ++mb) {
    const uint2 up_ = uTb[mb*1024 + j];
    const v2f uj01 = unpk(up_.x), uj23 = unpk(up_.y);
    const v2f z = {0.f, 0.f};
    {
      const float* ab = sA0 + 8 + mb*20;
      const v2f h01 = __builtin_elementwise_max(*(const v2f*)(ab+16) - uj01, z);
      const v2f h23 = __builtin_elementwise_max(*(const v2f*)(ab+18) - uj23, z);
      g0a = fma2(h01, *(const v2f*)(ab+ 0), g0a); g0a = fma2(h23, *(const v2f*)(ab+ 2), g0a);
      g0b = fma2(h01, *(const v2f*)(ab+ 4), g0b); g0b = fma2(h23, *(const v2f*)(ab+ 6), g0b);
      g0c = fma2(h01, *(const v2f*)(ab+ 8), g0c); g0c = fma2(h23, *(const v2f*)(ab+10), g0c);
      g0d = fma2(h01, *(const v2f*)(ab+12), g0d); g0d = fma2(h23, *(const v2f*)(ab+14), g0d);
    }
    {
      const float* ab = sA1 + 8 + mb*20;
      const v2f h01 = __builtin_elementwise_max(*(const v2f*)(ab+16) - uj01, z);
      const v2f h23 = __builtin_elementwise_max(*(const v2f*)(ab+18) - uj23, z);
      g1a = fma2(h01, *(const v2f*)(ab+ 0), g1a); g1a = fma2(h23, *(const v2f*)(ab+ 2), g1a);
      g1b = fma2(h01, *(const v2f*)(ab+ 4), g1b); g1b = fma2(h23, *(const v2f*)(ab+ 6), g1b);
      g1c = fma2(h01, *(const v2f*)(ab+ 8), g1c); g1c = fma2(h23, *(const v2f*)(ab+10), g1c);
      g1d = fma2(h01, *(const v2f*)(ab+12), g1d); g1d = fma2(h23, *(const v2f*)(ab+14), g1d);
    }
  }

  // collapse geom v2f accumulators to scalars; qk adds into the scalars
  float t0a = g0a.x + g0a.y, t0b = g0b.x + g0b.y;
  float t0c = g0c.x + g0c.y, t0d = g0d.x + g0d.y;
  float t1a = g1a.x + g1a.y, t1b = g1b.x + g1b.y;
  float t1c = g1c.x + g1c.y, t1d = g1d.x + g1d.y;

  // ---- qk via v_dot2_f32_f16 (k and q both packed f16 pairs) ----
  {
    const unsigned int* qT0 = qT + i0*64;
    const unsigned int* qT1 = qT0 + 64;
    #pragma unroll 8
    for (int cb = 0; cb < 8; ++cb) {
      const uint2 kp0 = kTb[(cb     )*1024 + j];
      const uint2 kp1 = kTb[(cb +  8)*1024 + j];
      const uint2 kp2 = kTb[(cb + 16)*1024 + j];
      const uint2 kp3 = kTb[(cb + 24)*1024 + j];
      t0a = fdot2h(kp0.x, qT0[     cb*2], t0a); t0a = fdot2h(kp0.y, qT0[     cb*2+1], t0a);
      t0b = fdot2h(kp1.x, qT0[16 + cb*2], t0b); t0b = fdot2h(kp1.y, qT0[16 + cb*2+1], t0b);
      t0c = fdot2h(kp2.x, qT0[32 + cb*2], t0c); t0c = fdot2h(kp2.y, qT0[32 + cb*2+1], t0c);
      t0d = fdot2h(kp3.x, qT0[48 + cb*2], t0d); t0d = fdot2h(kp3.y, qT0[48 + cb*2+1], t0d);
      t1a = fdot2h(kp0.x, qT1[     cb*2], t1a); t1a = fdot2h(kp0.y, qT1[     cb*2+1], t1a);
      t1b = fdot2h(kp1.x, qT1[16 + cb*2], t1b); t1b = fdot2h(kp1.y, qT1[16 + cb*2+1], t1b);
      t1c = fdot2h(kp2.x, qT1[32 + cb*2], t1c); t1c = fdot2h(kp2.y, qT1[32 + cb*2+1], t1c);
      t1d = fdot2h(kp3.x, qT1[48 + cb*2], t1d); t1d = fdot2h(kp3.y, qT1[48 + cb*2+1], t1d);
    }
  }

  // ---- exp2 numerators (rounded to f16-representable) -> wave-private E ----
  float lsum[8];
  float* eW = &eL[w*544];
  {
    const float p0 = r2hf(exp2f(t0a + (c00 - dist0)));
    const float p1 = r2hf(exp2f(t0b + (c01 - dist0)));
    const float p2 = r2hf(exp2f(t0c + (c02 - dist0)));
    const float p3 = r2hf(exp2f(t0d + (c03 - dist0)));
    lsum[0] = p0; lsum[1] = p1; lsum[2] = p2; lsum[3] = p3;
    eW[      lane] = p0; eW[ 68 + lane] = p1; eW[136 + lane] = p2; eW[204 + lane] = p3;
    const float r0 = r2hf(exp2f(t1a + (c10 - dist1)));
    const float r1 = r2hf(exp2f(t1b + (c11 - dist1)));
    const float r2 = r2hf(exp2f(t1c + (c12 - dist1)));
    const float r3 = r2hf(exp2f(t1d + (c13 - dist1)));
    lsum[4] = r0; lsum[5] = r1; lsum[6] = r2; lsum[7] = r3;
    eW[272 + lane] = r0; eW[340 + lane] = r1; eW[408 + lane] = r2; eW[476 + lane] = r3;
  }
  __builtin_amdgcn_wave_barrier();

  // ---- denominator reduce first (frees lsum before PV raises pressure) ----
  #pragma unroll
  for (int mm = 1; mm < 64; mm <<= 1) {
    #pragma unroll
    for (int r8 = 0; r8 < 8; ++r8) lsum[r8] += __shfl_xor(lsum[r8], mm);
  }
  if (lane == 0) {
    #pragma unroll
    for (int r8 = 0; r8 < 8; ++r8) rden[w*8 + r8] = lsum[r8];
  }

  // ---- PV: lane owns col-quad c4 (head hh), rep = jp-half of tile.
  //      v is f16x2 over j-pairs; e pairs packed in-lane (exact: pre-rounded) ----
  v4f acc0 = {0.f,0.f,0.f,0.f};
  v4f acc1 = {0.f,0.f,0.f,0.f};
  {
    const float* er0 = &eL[w*544 +  hh   *68 + rep*32];
    const float* er1 = &eL[w*544 + (4+hh)*68 + rep*32];
    const uint4* vg = (const uint4*)vJ + (w*32 + rep*16)*32 + c4;
    #pragma unroll 4
    for (int m = 0; m < 16; ++m) {
      const uint4 vw = vg[m*32];
      const unsigned int e0 = pkh(er0[2*m], er0[2*m+1]);
      const unsigned int e1 = pkh(er1[2*m], er1[2*m+1]);
      acc0.x = fdot2h(vw.x, e0, acc0.x); acc0.y = fdot2h(vw.y, e0, acc0.y);
      acc0.z = fdot2h(vw.z, e0, acc0.z); acc0.w = fdot2h(vw.w, e0, acc0.w);
      acc1.x = fdot2h(vw.x, e1, acc1.x); acc1.y = fdot2h(vw.y, e1, acc1.y);
      acc1.z = fdot2h(vw.z, e1, acc1.z); acc1.w = fdot2h(vw.w, e1, acc1.w);
    }
  }
  __builtin_amdgcn_wave_barrier();

  // ---- in-block reduce across 16 waves ----
  ((v4f*)rnum)[((w*2+0)*2 + rep)*32 + c4] = acc0;
  ((v4f*)rnum)[((w*2+1)*2 + rep)*32 + c4] = acc1;
  __syncthreads();

  if (t < 256) {
    const int ii = t >> 7, c = t & 127;
    float num = 0.f, den = 0.f;
    #pragma unroll
    for (int ww = 0; ww < 16; ++ww) {
      num += rnum[((ww*2+ii)*2+0)*128 + c];
      num += rnum[((ww*2+ii)*2+1)*128 + c];
      den += rden[ww*8 + ii*4 + (c>>5)];
    }
    out[(i0+ii)*128 + c] = num / den;
  }
}

extern "C" void kernel_launch(void* const* d_in, const int* in_sizes, int n_in,
                              void* d_out, int out_size, void* d_ws, size_t ws_size,
                              hipStream_t stream) {
  const float* x   = (const float*)d_in[0];
  const float* y   = (const float*)d_in[1];
  const float* pos = (const float*)d_in[2];
  const float* Wq  = (const float*)d_in[3];
  const float* bq  = (const float*)d_in[4];
  const float* Wk  = (const float*)d_in[5];
  const float* bk  = (const float*)d_in[6];
  const float* Wv  = (const float*)d_in[7];
  const float* bv  = (const float*)d_in[8];
  const float* W1  = (const float*)d_in[9];
  const float* b1  = (const float*)d_in[10];
  const float* W2  = (const float*)d_in[11];
  const float* b2  = (const float*)d_in[12];

  float* ws = (float*)d_ws;
  unsigned int* qT   = (unsigned int*)ws;               // 65536 u32 (region 131072 f)
  unsigned int* vJ   = (unsigned int*)(ws + 131072);    // 65536 u32 (region 131072 f)
  unsigned int* kTb  = (unsigned int*)(ws + 262144);    // 65536 u32
  unsigned int* uTb  = (unsigned int*)(ws + 327680);    // 32768 u32
  float*        sA   = ws + 360448;                     // 335872
  float*        pos4 = ws + 696320;                     // 4096
  float*        out  = (float*)d_out;

  k_pre<<<dim3(512), dim3(384), 0, stream>>>(x, y, pos, Wq, bq, Wk, bk, Wv, bv,
                                             W1, b1, W2, b2,
                                             qT, vJ, kTb, uTb, sA, pos4);
  k_attn<<<dim3(512), dim3(1024), 0, stream>>>(qT, vJ, (const uint2*)kTb,
                                               (const uint2*)uTb, sA,
                                               (const v4f*)pos4, out);
}

// Round 6
// 108.618 us; speedup vs baseline: 1.4604x; 1.0506x over previous
//
#include <hip/hip_runtime.h>
#include <hip/hip_fp16.h>
#include <math.h>

// N=1024, C=128, H=4, HD=32, HID=64
//   u[n,m]   = pos[n,:] @ W1[:,m]       (hid[i,j,m] = (u[i,m]+b1[m]) - u[j,m])
//   A[n,h,m] = sum_d q[n,h*32+d] * W2[m, h*32+d]
//   c[n,h]   = sum_d q[n,h*32+d] * b2[h*32+d]
//   score[h,i,j] = (q_i.k_j)/sqrt(32) + sum_m relu(hid)*A[i,h,m] + c[i,h] - dist(i,j)
//   softmax via exp2 (q pre-scaled RS*log2e; A/c/pos pre-scaled log2e)
//
// R16 = R15 (114.1 us) + dwordx4 widening of the k and u streams using
//   R14's layouts (kT8: all 4 head-quads of a cb contiguous -> 2x uint4
//   per cb; uT4: 2 mb per uint4). Loads/thread 64 -> 40. R14's spill came
//   from the eb[8]+shfl-pack live range (VGPR 32 + 88MB scratch), NOT the
//   layouts; this version keeps R15's register structure (zero delta for
//   kT8: ka+kb = 8 u32 = 4x uint2; +2 u32 for uT4).
//
// ws layout (floats):
//   qT   u32[1024][64] f16x2 pairs                     @ 0
//   vJ   u32[512][128]: f16x2 (v[2jp][c], v[2jp+1][c]) @ 131072
//   kT8  u32[8][1024][8]: f16x2 k quads grouped        @ 262144
//   uT4  u32[8][1024][4]: bf16x2 u quads grouped       @ 327680
//   sA   [1024][328]                                   @ 360448
//   pos4 [1024][4] (x L2E)                             @ 696320

typedef float v2f __attribute__((ext_vector_type(2)));
typedef float v4f __attribute__((ext_vector_type(4)));
typedef __fp16 h2f __attribute__((ext_vector_type(2)));

#define L2E 1.4426950408889634f
#define RSL (0.17677669529663687f * L2E)

static __device__ __forceinline__ float dot4(float4 a, float4 b) {
  return a.x*b.x + a.y*b.y + a.z*b.z + a.w*b.w;
}
static __device__ __forceinline__ v2f fma2(v2f a, v2f b, v2f c) {
  return __builtin_elementwise_fma(a, b, c);
}
static __device__ __forceinline__ unsigned int bfr(float f) {   // fp32 -> bf16 (RNE)
  unsigned int b = __float_as_uint(f);
  return (b + 0x7fffu + ((b >> 16) & 1u)) >> 16;
}
static __device__ __forceinline__ unsigned int pack2(float lo, float hi) {
  return bfr(lo) | (bfr(hi) << 16);
}
static __device__ __forceinline__ v2f unpk(unsigned int a) {    // bf16x2 -> 2x fp32
  v2f r;
  r.x = __uint_as_float(a << 16);
  r.y = __uint_as_float(a & 0xffff0000u);
  return r;
}
static __device__ __forceinline__ unsigned int pkh(float lo, float hi) { // f16x2 (RTZ)
  h2f r = __builtin_amdgcn_cvt_pkrtz(lo, hi);
  return __builtin_bit_cast(unsigned int, r);
}
static __device__ __forceinline__ unsigned int pkrn(float lo, float hi) { // f16x2 (RNE)
  unsigned int a = (unsigned int)__half_as_ushort(__float2half(lo));
  unsigned int b = (unsigned int)__half_as_ushort(__float2half(hi));
  return a | (b << 16);
}
static __device__ __forceinline__ float fdot2h(unsigned int a_, unsigned int b_, float acc) {
  return __builtin_amdgcn_fdot2(__builtin_bit_cast(h2f, a_),
                                __builtin_bit_cast(h2f, b_), acc, false);
}
static __device__ __forceinline__ float r2hf(float x) { // round f32 to f16-representable
  h2f t = __builtin_amdgcn_cvt_pkrtz(x, x);
  return (float)t.x;
}

// ---------------- K1: precompute ------------------------------------------
// 512 blocks x 384 thr; block = 2 rows.
__global__ __launch_bounds__(384) void k_pre(
    const float* __restrict__ x, const float* __restrict__ y, const float* __restrict__ pos,
    const float* __restrict__ Wq, const float* __restrict__ bq,
    const float* __restrict__ Wk, const float* __restrict__ bk,
    const float* __restrict__ Wv, const float* __restrict__ bv,
    const float* __restrict__ W1, const float* __restrict__ b1,
    const float* __restrict__ W2, const float* __restrict__ b2,
    unsigned int* __restrict__ qT, unsigned int* __restrict__ vJ,
    unsigned int* __restrict__ kT8, unsigned int* __restrict__ uT4,
    float* __restrict__ sA, float* __restrict__ pos4w)
{
  __shared__ float xs[256], ys[256], qs[256];
  __shared__ __align__(16) float4 W2S[64*33];

  const int t  = threadIdx.x;
  const int n0 = blockIdx.x * 2;

  if (t < 256) { xs[t] = x[n0*128 + t]; ys[t] = y[n0*128 + t]; }
  {
    const float4* w2g = (const float4*)W2;
    #pragma unroll
    for (int r = 0; r < 6; ++r) {
      const int e = t + 384*r;
      if (e < 2048) W2S[(e>>5)*33 + (e&31)] = w2g[e];
    }
  }
  __syncthreads();

  {
    const int c   = t & 127;
    const int mat = t >> 7;                 // wave-uniform
    const float* W    = (mat == 0) ? Wq : (mat == 1 ? Wk : Wv);
    const float* S    = (mat == 0) ? xs : ys;
    const float* bias = (mat == 0) ? bq : (mat == 1 ? bk : bv);
    float a0 = 0.f, a1 = 0.f;
    #pragma unroll 8
    for (int d = 0; d < 128; ++d) {
      const float w_ = W[d*128 + c];
      a0 = fmaf(S[d],       w_, a0);
      a1 = fmaf(S[128 + d], w_, a1);
    }
    const float bb = bias[c];
    a0 += bb; a1 += bb;
    if (mat == 0) {
      qs[c] = a0; qs[128 + c] = a1;
      // q: pack adjacent columns into f16x2 pairs (pre-scaled by RSL)
      const float sa0 = a0 * RSL, sa1 = a1 * RSL;
      const float tb0 = __shfl_xor(sa0, 1);
      const float tb1 = __shfl_xor(sa1, 1);
      if ((c & 1) == 0) {
        qT[(n0  )*64 + (c>>1)] = pkh(sa0, tb0);
        qT[(n0+1)*64 + (c>>1)] = pkh(sa1, tb1);
      }
    } else if (mat == 2) {
      // v: pack the two rows (n0, n0+1) per column -> f16x2 (RNE)
      vJ[(n0>>1)*128 + c] = pkrn(a0, a1);
    } else {
      // k: pack adjacent columns via in-wave exchange; grouped layout:
      // kT8[(cb*1024 + n)*8 + slot*2 + wrd], qi=c>>2, cb=qi&7, slot=qi>>3
      const float b0 = __shfl_xor(a0, 1);
      const float b1 = __shfl_xor(a1, 1);
      if ((c & 1) == 0) {
        const int qi = c >> 2, cbv = qi & 7, slot = qi >> 3, wrd = (c >> 1) & 1;
        const int base = (cbv*1024 + n0)*8 + slot*2 + wrd;
        kT8[base]     = pkh(a0, b0);
        kT8[base + 8] = pkh(a1, b1);
      }
    }
  }
  __syncthreads();

  if (t < 256) {
    const int m = t & 63, h = t >> 6;
    const float4* qs4 = (const float4*)qs;
    #pragma unroll
    for (int ii = 0; ii < 2; ++ii) {
      float acc = 0.f;
      #pragma unroll
      for (int ch = 0; ch < 8; ++ch)
        acc += dot4(qs4[ii*32 + h*8 + ch], W2S[m*33 + h*8 + ch]);
      sA[(n0+ii)*328 + 8 + (m>>2)*20 + h*4 + (m&3)] = acc * L2E;
    }
    if (t < 8) {
      const int ii = t >> 2, h2 = t & 3;
      float ca = 0.f;
      #pragma unroll
      for (int d = 0; d < 32; ++d) ca = fmaf(qs[ii*128 + h2*32 + d], b2[h2*32 + d], ca);
      sA[(n0+ii)*328 + h2] = ca * L2E;
    } else if (t < 16) {
      const int tt = t-8, ii = tt>>2, cc = tt&3;
      sA[(n0+ii)*328 + 4 + cc] = (cc < 3) ? pos[(n0+ii)*3 + cc] * L2E : 0.f;
    } else if (t < 24) {
      const int tt = t-16, ii = tt>>2, cc = tt&3;
      pos4w[(n0+ii)*4 + cc] = (cc < 3) ? pos[(n0+ii)*3 + cc] * L2E : 0.f;
    }
  } else if (t < 320) {
    // u: thread = (ii, m-pair); grouped layout: uT4[((mp>>2)*1024 + n)*4 + (mp&3)]
    const int tt = t - 256, ii = tt >> 5, mp = tt & 31;
    const int m0 = mp * 2;
    float ua0 = 0.f, ua1 = 0.f;
    #pragma unroll
    for (int cc = 0; cc < 3; ++cc) {
      const float p = pos[(n0+ii)*3 + cc];
      ua0 = fmaf(p, W1[cc*64 + m0    ], ua0);
      ua1 = fmaf(p, W1[cc*64 + m0 + 1], ua1);
    }
    sA[(n0+ii)*328 + 8 + (m0>>2)*20 + 16 + (m0&3)    ] = ua0 + b1[m0];
    sA[(n0+ii)*328 + 8 + (m0>>2)*20 + 16 + (m0&3) + 1] = ua1 + b1[m0+1];
    uT4[((mp>>2)*1024 + (n0+ii))*4 + (mp&3)] = pack2(ua0, ua1);
  }
}

// ---------------- K2: fused scores + softmax + PV + direct out -------------
// 512 blocks x 1024 thr (16 waves). Block = 2 i-rows x ALL j; wave w = j-tile w.
__global__ __launch_bounds__(1024, 8) void k_attn(
    const unsigned int* __restrict__ qT, const unsigned int* __restrict__ vJ,
    const unsigned int* __restrict__ kT8, const unsigned int* __restrict__ uT4,
    const float* __restrict__ sA, const v4f* __restrict__ pos4,
    float* __restrict__ out)
{
  __shared__ __align__(16) float eL[16*544];   // per-wave E: [(ii*4+h)*68 + j]
  __shared__ __align__(16) float rnum[8192];   // v4f [w][ii][rep][c4]
  __shared__ float rden[128];                  // [w][ii*4+h]

  const int t     = threadIdx.x;
  const int i0    = blockIdx.x * 2;
  const int w     = t >> 6;                    // 0..15 = j-tile
  const int lane  = t & 63;
  const int c4    = lane & 31;
  const int rep   = lane >> 5;
  const int hh    = c4 >> 3;

  const int jb = w*64;
  const int j  = jb + lane;

  const float* sA0 = sA + i0*328;              // uniform -> scalar loads
  const float* sA1 = sA0 + 328;

  const float c00 = sA0[0], c01 = sA0[1], c02 = sA0[2], c03 = sA0[3];
  const float c10 = sA1[0], c11 = sA1[1], c12 = sA1[2], c13 = sA1[3];
  const float p0x = sA0[4], p0y = sA0[5], p0z = sA0[6];
  const float p1x = sA1[4], p1y = sA1[5], p1z = sA1[6];

  const v4f pj = pos4[j];
  const float d0x = p0x-pj.x, d0y = p0y-pj.y, d0z = p0z-pj.z;
  const float d1x = p1x-pj.x, d1y = p1y-pj.y, d1z = p1z-pj.z;
  const float dist0 = sqrtf(d0x*d0x + d0y*d0y + d0z*d0z);
  const float dist1 = sqrtf(d1x*d1x + d1y*d1y + d1z*d1z);

  // ---- geom (packed math, bf16 u stream, uint4-grouped: 8 loads) ----
  v2f g0a={0.f,0.f}, g0b={0.f,0.f}, g0c={0.f,0.f}, g0d={0.f,0.f};
  v2f g1a={0.f,0.f}, g1b={0.f,0.f}, g1c={0.f,0.f}, g1d={0.f,0.f};
  {
    const uint4* ug = (const uint4*)uT4;
#define GEOM_MB(MB, W01, W23) { \
    const v2f uj01 = unpk(W01), uj23 = unpk(W23); \
    const v2f z = {0.f, 0.f}; \
    { \
      const float* ab = sA0 + 8 + (MB)*20; \
      const v2f h01 = __builtin_elementwise_max(*(const v2f*)(ab+16) - uj01, z); \
      const v2f h23 = __builtin_elementwise_max(*(const v2f*)(ab+18) - uj23, z); \
      g0a = fma2(h01, *(const v2f*)(ab+ 0), g0a); g0a = fma2(h23, *(const v2f*)(ab+ 2), g0a); \
      g0b = fma2(h01, *(const v2f*)(ab+ 4), g0b); g0b = fma2(h23, *(const v2f*)(ab+ 6), g0b); \
      g0c = fma2(h01, *(const v2f*)(ab+ 8), g0c); g0c = fma2(h23, *(const v2f*)(ab+10), g0c); \
      g0d = fma2(h01, *(const v2f*)(ab+12), g0d); g0d = fma2(h23, *(const v2f*)(ab+14), g0d); \
    } \
    { \
      const float* ab = sA1 + 8 + (MB)*20; \
      const v2f h01 = __builtin_elementwise_max(*(const v2f*)(ab+16) - uj01, z); \
      const v2f h23 = __builtin_elementwise_max(*(const v2f*)(ab+18) - uj23, z); \
      g1a = fma2(h01, *(const v2f*)(ab+ 0), g1a); g1a = fma2(h23, *(const v2f*)(ab+ 2), g1a); \
      g1b = fma2(h01, *(const v2f*)(ab+ 4), g1b); g1b = fma2(h23, *(const v2f*)(ab+ 6), g1b); \
      g1c = fma2(h01, *(const v2f*)(ab+ 8), g1c); g1c = fma2(h23, *(const v2f*)(ab+10), g1c); \
      g1d = fma2(h01, *(const v2f*)(ab+12), g1d); g1d = fma2(h23, *(const v2f*)(ab+14), g1d); \
    } \
  }
    #pragma unroll 2
    for (int g = 0; g < 8; ++g) {
      const uint4 uw = ug[g*1024 + j];
      GEOM_MB(2*g,     uw.x, uw.y)
      GEOM_MB(2*g + 1, uw.z, uw.w)
    }
#undef GEOM_MB
  }

  // collapse geom v2f accumulators to scalars; qk adds into the scalars
  float t0a = g0a.x + g0a.y, t0b = g0b.x + g0b.y;
  float t0c = g0c.x + g0c.y, t0d = g0d.x + g0d.y;
  float t1a = g1a.x + g1a.y, t1b = g1b.x + g1b.y;
  float t1c = g1c.x + g1c.y, t1d = g1d.x + g1d.y;

  // ---- qk via v_dot2_f32_f16 (grouped kT8: 2 x dwordx4 per cb) ----
  {
    const uint4* kg = (const uint4*)kT8;
    const unsigned int* qT0 = qT + i0*64;
    const unsigned int* qT1 = qT0 + 64;
    #pragma unroll 8
    for (int cb = 0; cb < 8; ++cb) {
      const uint4 ka = kg[(cb*1024 + j)*2];
      const uint4 kb = kg[(cb*1024 + j)*2 + 1];
      t0a = fdot2h(ka.x, qT0[     cb*2], t0a); t0a = fdot2h(ka.y, qT0[     cb*2+1], t0a);
      t0b = fdot2h(ka.z, qT0[16 + cb*2], t0b); t0b = fdot2h(ka.w, qT0[16 + cb*2+1], t0b);
      t0c = fdot2h(kb.x, qT0[32 + cb*2], t0c); t0c = fdot2h(kb.y, qT0[32 + cb*2+1], t0c);
      t0d = fdot2h(kb.z, qT0[48 + cb*2], t0d); t0d = fdot2h(kb.w, qT0[48 + cb*2+1], t0d);
      t1a = fdot2h(ka.x, qT1[     cb*2], t1a); t1a = fdot2h(ka.y, qT1[     cb*2+1], t1a);
      t1b = fdot2h(ka.z, qT1[16 + cb*2], t1b); t1b = fdot2h(ka.w, qT1[16 + cb*2+1], t1b);
      t1c = fdot2h(kb.x, qT1[32 + cb*2], t1c); t1c = fdot2h(kb.y, qT1[32 + cb*2+1], t1c);
      t1d = fdot2h(kb.z, qT1[48 + cb*2], t1d); t1d = fdot2h(kb.w, qT1[48 + cb*2+1], t1d);
    }
  }

  // ---- exp2 numerators (rounded to f16-representable) -> wave-private E ----
  float lsum[8];
  float* eW = &eL[w*544];
  {
    const float p0 = r2hf(exp2f(t0a + (c00 - dist0)));
    const float p1 = r2hf(exp2f(t0b + (c01 - dist0)));
    const float p2 = r2hf(exp2f(t0c + (c02 - dist0)));
    const float p3 = r2hf(exp2f(t0d + (c03 - dist0)));
    lsum[0] = p0; lsum[1] = p1; lsum[2] = p2; lsum[3] = p3;
    eW[      lane] = p0; eW[ 68 + lane] = p1; eW[136 + lane] = p2; eW[204 + lane] = p3;
    const float r0 = r2hf(exp2f(t1a + (c10 - dist1)));
    const float r1 = r2hf(exp2f(t1b + (c11 - dist1)));
    const float r2 = r2hf(exp2f(t1c + (c12 - dist1)));
    const float r3 = r2hf(exp2f(t1d + (c13 - dist1)));
    lsum[4] = r0; lsum[5] = r1; lsum[6] = r2; lsum[7] = r3;
    eW[272 + lane] = r0; eW[340 + lane] = r1; eW[408 + lane] = r2; eW[476 + lane] = r3;
  }
  __builtin_amdgcn_wave_barrier();

  // ---- denominator reduce first (frees lsum before PV raises pressure) ----
  #pragma unroll
  for (int mm = 1; mm < 64; mm <<= 1) {
    #pragma unroll
    for (int r8 = 0; r8 < 8; ++r8) lsum[r8] += __shfl_xor(lsum[r8], mm);
  }
  if (lane == 0) {
    #pragma unroll
    for (int r8 = 0; r8 < 8; ++r8) rden[w*8 + r8] = lsum[r8];
  }

  // ---- PV: lane owns col-quad c4 (head hh), rep = jp-half of tile.
  //      v is f16x2 over j-pairs; e pairs packed in-lane (exact: pre-rounded) ----
  v4f acc0 = {0.f,0.f,0.f,0.f};
  v4f acc1 = {0.f,0.f,0.f,0.f};
  {
    const float* er0 = &eL[w*544 +  hh   *68 + rep*32];
    const float* er1 = &eL[w*544 + (4+hh)*68 + rep*32];
    const uint4* vg = (const uint4*)vJ + (w*32 + rep*16)*32 + c4;
    #pragma unroll 4
    for (int m = 0; m < 16; ++m) {
      const uint4 vw = vg[m*32];
      const unsigned int e0 = pkh(er0[2*m], er0[2*m+1]);
      const unsigned int e1 = pkh(er1[2*m], er1[2*m+1]);
      acc0.x = fdot2h(vw.x, e0, acc0.x); acc0.y = fdot2h(vw.y, e0, acc0.y);
      acc0.z = fdot2h(vw.z, e0, acc0.z); acc0.w = fdot2h(vw.w, e0, acc0.w);
      acc1.x = fdot2h(vw.x, e1, acc1.x); acc1.y = fdot2h(vw.y, e1, acc1.y);
      acc1.z = fdot2h(vw.z, e1, acc1.z); acc1.w = fdot2h(vw.w, e1, acc1.w);
    }
  }
  __builtin_amdgcn_wave_barrier();

  // ---- in-block reduce across 16 waves ----
  ((v4f*)rnum)[((w*2+0)*2 + rep)*32 + c4] = acc0;
  ((v4f*)rnum)[((w*2+1)*2 + rep)*32 + c4] = acc1;
  __syncthreads();

  if (t < 256) {
    const int ii = t >> 7, c = t & 127;
    float num = 0.f, den = 0.f;
    #pragma unroll
    for (int ww = 0; ww < 16; ++ww) {
      num += rnum[((ww*2+ii)*2+0)*128 + c];
      num += rnum[((ww*2+ii)*2+1)*128 + c];
      den += rden[ww*8 + ii*4 + (c>>5)];
    }
    out[(i0+ii)*128 + c] = num / den;
  }
}

extern "C" void kernel_launch(void* const* d_in, const int* in_sizes, int n_in,
                              void* d_out, int out_size, void* d_ws, size_t ws_size,
                              hipStream_t stream) {
  const float* x   = (const float*)d_in[0];
  const float* y   = (const float*)d_in[1];
  const float* pos = (const float*)d_in[2];
  const float* Wq  = (const float*)d_in[3];
  const float* bq  = (const float*)d_in[4];
  const float* Wk  = (const float*)d_in[5];
  const float* bk  = (const float*)d_in[6];
  const float* Wv  = (const float*)d_in[7];
  const float* bv  = (const float*)d_in[8];
  const float* W1  = (const float*)d_in[9];
  const float* b1  = (const float*)d_in[10];
  const float* W2  = (const float*)d_in[11];
  const float* b2  = (const float*)d_in[12];

  float* ws = (float*)d_ws;
  unsigned int* qT   = (unsigned int*)ws;               // 65536 u32 (region 131072 f)
  unsigned int* vJ   = (unsigned int*)(ws + 131072);    // 65536 u32 (region 131072 f)
  unsigned int* kT8  = (unsigned int*)(ws + 262144);    // 65536 u32
  unsigned int* uT4  = (unsigned int*)(ws + 327680);    // 32768 u32
  float*        sA   = ws + 360448;                     // 335872
  float*        pos4 = ws + 696320;                     // 4096
  float*        out  = (float*)d_out;

  k_pre<<<dim3(512), dim3(384), 0, stream>>>(x, y, pos, Wq, bq, Wk, bk, Wv, bv,
                                             W1, b1, W2, b2,
                                             qT, vJ, kT8, uT4, sA, pos4);
  k_attn<<<dim3(512), dim3(1024), 0, stream>>>(qT, vJ, kT8, uT4, sA,
                                               (const v4f*)pos4, out);
}